// Round 1
// baseline (17998.729 us; speedup 1.0000x reference)
//
#include <hip/hip_runtime.h>
#include <math.h>

#define N_LAYERS 24
#define D_MODEL 768
#define D_INNER 1536
#define D_STATE 16
#define DT_RANK 48
#define D_CONV 4
#define VOCAB 50280
#define ENC_DIM 256
#define SEQ 512
#define BATCH 2
#define NTOK (SEQ*BATCH)        // 1024 tokens (b,l) row-major as b*SEQ+l
#define XZ_DIM (2*D_INNER)      // 3072
#define PROJ_DIM (DT_RANK + 2*D_STATE)  // 80

__device__ __forceinline__ float sigmoidf_(float x) { return 1.f / (1.f + __expf(-x)); }
__device__ __forceinline__ float softplusf_(float x) {
    return fmaxf(x, 0.f) + log1pf(__expf(-fabsf(x)));
}

// ---------------------------------------------------------------------------
// Transpose x (SEQ,BATCH,ENC) -> xt (BATCH,SEQ,ENC) so token rows match h.
__global__ __launch_bounds__(256) void transpose_x_k(const float* __restrict__ x,
                                                     float* __restrict__ xt) {
    int i = blockIdx.x * 256 + threadIdx.x;
    if (i >= SEQ * BATCH * ENC_DIM) return;
    int e = i % ENC_DIM;
    int b = (i / ENC_DIM) % BATCH;
    int l = i / (ENC_DIM * BATCH);
    xt[((size_t)(b * SEQ + l)) * ENC_DIM + e] = x[i];
}

// ---------------------------------------------------------------------------
// RMSNorm: one block per token row (D_MODEL=768)
__global__ __launch_bounds__(256) void rmsnorm_k(const float* __restrict__ in,
                                                 const float* __restrict__ w,
                                                 float* __restrict__ out) {
    int row = blockIdx.x;
    const float* r = in + (size_t)row * D_MODEL;
    float s = 0.f;
    for (int i = threadIdx.x; i < D_MODEL; i += 256) { float v = r[i]; s += v * v; }
    for (int o = 32; o > 0; o >>= 1) s += __shfl_down(s, o);
    __shared__ float wsum[4];
    int wave = threadIdx.x >> 6;
    if ((threadIdx.x & 63) == 0) wsum[wave] = s;
    __syncthreads();
    float tot = wsum[0] + wsum[1] + wsum[2] + wsum[3];
    float scale = rsqrtf(tot / (float)D_MODEL + 1e-5f);
    for (int i = threadIdx.x; i < D_MODEL; i += 256)
        out[(size_t)row * D_MODEL + i] = r[i] * scale * w[i];
}

// ---------------------------------------------------------------------------
// Generic fp32 NT GEMM: C[M,N] = A[M,K] @ B[N,K]^T  (+ epilogue per MODE)
// MODE 0: plain store
// MODE 1: += bias[n]
// MODE 2: softplus(acc + bias[n])
// MODE 3: C[m,n] += acc (residual accumulate)
// Requirements: M % 64 == 0, K % 16 == 0, lda/ldb multiples of 4 (float4 loads).
#define TS 64
#define BK 16
template<int MODE>
__global__ __launch_bounds__(256)
void gemm_nt(const float* __restrict__ A, const float* __restrict__ B,
             const float* __restrict__ bias, float* __restrict__ C,
             int M, int N, int K, int lda, int ldb, int ldc)
{
    __shared__ float As[BK][TS];
    __shared__ float Bs[BK][TS];
    int bm = blockIdx.y * TS;
    int bn = blockIdx.x * TS;
    int tid = threadIdx.x;
    int tx = tid & 15, ty = tid >> 4;
    int lrow = tid >> 2;          // 0..63
    int lkk  = (tid & 3) * 4;     // 0,4,8,12
    float acc[4][4] = {};

    for (int k0 = 0; k0 < K; k0 += BK) {
        // stage A tile (64 rows x 16 k), transposed into As[k][m]
        {
            const float* src = A + (size_t)(bm + lrow) * lda + (k0 + lkk);
            float4 v = *(const float4*)src;
            As[lkk + 0][lrow] = v.x;
            As[lkk + 1][lrow] = v.y;
            As[lkk + 2][lrow] = v.z;
            As[lkk + 3][lrow] = v.w;
        }
        // stage B tile with N guard
        {
            int brow = bn + lrow;
            float4 v = make_float4(0.f, 0.f, 0.f, 0.f);
            if (brow < N) v = *(const float4*)(B + (size_t)brow * ldb + (k0 + lkk));
            Bs[lkk + 0][lrow] = v.x;
            Bs[lkk + 1][lrow] = v.y;
            Bs[lkk + 2][lrow] = v.z;
            Bs[lkk + 3][lrow] = v.w;
        }
        __syncthreads();
        #pragma unroll
        for (int k = 0; k < BK; ++k) {
            float4 a4 = *(const float4*)&As[k][ty * 4];
            float4 b4 = *(const float4*)&Bs[k][tx * 4];
            float a[4] = {a4.x, a4.y, a4.z, a4.w};
            float b[4] = {b4.x, b4.y, b4.z, b4.w};
            #pragma unroll
            for (int i = 0; i < 4; ++i)
                #pragma unroll
                for (int j = 0; j < 4; ++j)
                    acc[i][j] = fmaf(a[i], b[j], acc[i][j]);
        }
        __syncthreads();
    }

    #pragma unroll
    for (int i = 0; i < 4; ++i) {
        int row = bm + ty * 4 + i;
        #pragma unroll
        for (int j = 0; j < 4; ++j) {
            int col = bn + tx * 4 + j;
            if (col < N) {
                float v = acc[i][j];
                if (MODE == 1) v += bias[col];
                if (MODE == 2) v = softplusf_(v + bias[col]);
                if (MODE == 3) v += C[(size_t)row * ldc + col];
                C[(size_t)row * ldc + col] = v;
            }
        }
    }
}

// ---------------------------------------------------------------------------
// Depthwise causal conv (k=4) + bias + SiLU.  xi is the first half of xz rows.
__global__ __launch_bounds__(256) void conv_silu_k(const float* __restrict__ xz,
                                                   const float* __restrict__ cw,
                                                   const float* __restrict__ cb,
                                                   float* __restrict__ xc) {
    int idx = blockIdx.x * 256 + threadIdx.x;
    if (idx >= NTOK * D_INNER) return;
    int d = idx % D_INNER;
    int m = idx / D_INNER;
    int l = m % SEQ;
    int b = m / SEQ;
    float acc = cb[d];
    #pragma unroll
    for (int j = 0; j < D_CONV; ++j) {
        int ll = l - (D_CONV - 1) + j;
        if (ll >= 0)
            acc = fmaf(cw[d * D_CONV + j], xz[(size_t)(b * SEQ + ll) * XZ_DIM + d], acc);
    }
    xc[(size_t)m * D_INNER + d] = acc * sigmoidf_(acc);
}

// ---------------------------------------------------------------------------
// Selective scan, parallel over (b, d, s): 16 lanes share one channel (b,d),
// each lane owns one state s. Reduction over s via shfl_xor within 16 lanes.
// Fused epilogue: y = (scan_out + D[d]*xc) * silu(z)
__global__ __launch_bounds__(256) void scan_k(const float* __restrict__ proj,
                                              const float* __restrict__ dtbuf,
                                              const float* __restrict__ xc,
                                              const float* __restrict__ xz,
                                              const float* __restrict__ A_log,
                                              const float* __restrict__ Dvec,
                                              float* __restrict__ y) {
    int t = blockIdx.x * 256 + threadIdx.x;   // 0 .. BATCH*D_INNER*D_STATE-1
    int s = t & (D_STATE - 1);
    int ch = t >> 4;
    int d = ch % D_INNER;
    int b = ch / D_INNER;
    float A = -__expf(A_log[d * D_STATE + s]);   // A_log stored per (d,s)
    float Dv = Dvec[d];
    float state = 0.f;
    for (int l = 0; l < SEQ; ++l) {
        int m = b * SEQ + l;
        float dtv = dtbuf[(size_t)m * D_INNER + d];
        float xcv = xc[(size_t)m * D_INNER + d];
        float Bv = proj[(size_t)m * PROJ_DIM + DT_RANK + s];
        float Cv = proj[(size_t)m * PROJ_DIM + DT_RANK + D_STATE + s];
        float da = __expf(dtv * A);
        state = fmaf(da, state, dtv * Bv * xcv);
        float contrib = state * Cv;
        contrib += __shfl_xor(contrib, 1);
        contrib += __shfl_xor(contrib, 2);
        contrib += __shfl_xor(contrib, 4);
        contrib += __shfl_xor(contrib, 8);
        if (s == 0) {
            float zv = xz[(size_t)m * XZ_DIM + D_INNER + d];
            float yv = (contrib + Dv * xcv) * (zv * sigmoidf_(zv));
            y[(size_t)m * D_INNER + d] = yv;
        }
    }
}

// ---------------------------------------------------------------------------
extern "C" void kernel_launch(void* const* d_in, const int* in_sizes, int n_in,
                              void* d_out, int out_size, void* d_ws, size_t ws_size,
                              hipStream_t stream) {
    const float* x           = (const float*)d_in[0];
    const float* W_et        = (const float*)d_in[1];
    const float* b_et        = (const float*)d_in[2];
    const float* in_proj_w   = (const float*)d_in[3];
    const float* conv_w      = (const float*)d_in[4];
    const float* conv_b      = (const float*)d_in[5];
    const float* x_proj_w    = (const float*)d_in[6];
    const float* dt_proj_w   = (const float*)d_in[7];
    const float* dt_proj_b   = (const float*)d_in[8];
    const float* A_log       = (const float*)d_in[9];
    const float* Dv          = (const float*)d_in[10];
    const float* out_proj_w  = (const float*)d_in[11];
    const float* norm_w      = (const float*)d_in[12];
    const float* final_norm_w= (const float*)d_in[13];
    const float* embed       = (const float*)d_in[14];
    float* out = (float*)d_out;
    float* ws  = (float*)d_ws;

    // workspace layout (floats); total ~9.52M floats = 38.1 MB
    float* h    = ws;                        // NTOK*D_MODEL
    float* hn   = h    + (size_t)NTOK * D_MODEL;
    float* xz   = hn   + (size_t)NTOK * D_MODEL;
    float* xc   = xz   + (size_t)NTOK * XZ_DIM;
    float* proj = xc   + (size_t)NTOK * D_INNER;
    float* dt   = proj + (size_t)NTOK * PROJ_DIM;
    float* yb   = dt   + (size_t)NTOK * D_INNER;   // reused as xt for encoder

    dim3 blk(256);

    // encoder: h = x @ W_et^T + b_et  (token-major)
    transpose_x_k<<<(SEQ * BATCH * ENC_DIM + 255) / 256, blk, 0, stream>>>(x, yb);
    gemm_nt<1><<<dim3(D_MODEL / 64, NTOK / 64), blk, 0, stream>>>(
        yb, W_et, b_et, h, NTOK, D_MODEL, ENC_DIM, ENC_DIM, ENC_DIM, D_MODEL);

    for (int L = 0; L < N_LAYERS; ++L) {
        const float* in_w = in_proj_w  + (size_t)L * XZ_DIM * D_MODEL;
        const float* cw   = conv_w     + (size_t)L * D_INNER * D_CONV;
        const float* cb   = conv_b     + (size_t)L * D_INNER;
        const float* xw   = x_proj_w   + (size_t)L * PROJ_DIM * D_INNER;
        const float* dtw  = dt_proj_w  + (size_t)L * D_INNER * DT_RANK;
        const float* dtb  = dt_proj_b  + (size_t)L * D_INNER;
        const float* Al   = A_log      + (size_t)L * D_INNER * D_STATE;
        const float* Dl   = Dv         + (size_t)L * D_INNER;
        const float* ow   = out_proj_w + (size_t)L * D_MODEL * D_INNER;
        const float* nw   = norm_w     + (size_t)L * D_MODEL;

        rmsnorm_k<<<NTOK, blk, 0, stream>>>(h, nw, hn);
        gemm_nt<0><<<dim3(XZ_DIM / 64, NTOK / 64), blk, 0, stream>>>(
            hn, in_w, nullptr, xz, NTOK, XZ_DIM, D_MODEL, D_MODEL, D_MODEL, XZ_DIM);
        conv_silu_k<<<(NTOK * D_INNER + 255) / 256, blk, 0, stream>>>(xz, cw, cb, xc);
        gemm_nt<0><<<dim3((PROJ_DIM + 63) / 64, NTOK / 64), blk, 0, stream>>>(
            xc, xw, nullptr, proj, NTOK, PROJ_DIM, D_INNER, D_INNER, D_INNER, PROJ_DIM);
        gemm_nt<2><<<dim3(D_INNER / 64, NTOK / 64), blk, 0, stream>>>(
            proj, dtw, dtb, dt, NTOK, D_INNER, DT_RANK, PROJ_DIM, DT_RANK, D_INNER);
        scan_k<<<(BATCH * D_INNER * D_STATE) / 256, blk, 0, stream>>>(
            proj, dt, xc, xz, Al, Dl, yb);
        gemm_nt<3><<<dim3(D_MODEL / 64, NTOK / 64), blk, 0, stream>>>(
            yb, ow, nullptr, h, NTOK, D_MODEL, D_INNER, D_INNER, D_INNER, D_MODEL);
    }

    rmsnorm_k<<<NTOK, blk, 0, stream>>>(h, final_norm_w, hn);
    gemm_nt<0><<<dim3((VOCAB + 63) / 64, NTOK / 64), blk, 0, stream>>>(
        hn, embed, nullptr, out, NTOK, VOCAB, D_MODEL, D_MODEL, D_MODEL, VOCAB);
}

// Round 2
// 16119.827 us; speedup vs baseline: 1.1166x; 1.1166x over previous
//
#include <hip/hip_runtime.h>
#include <math.h>

#define N_LAYERS 24
#define D_MODEL 768
#define D_INNER 1536
#define D_STATE 16
#define DT_RANK 48
#define D_CONV 4
#define VOCAB 50280
#define ENC_DIM 256
#define SEQ 512
#define BATCH 2
#define NTOK (SEQ*BATCH)
#define XZ_DIM (2*D_INNER)
#define PROJ_DIM (DT_RANK + 2*D_STATE)  // 80

typedef __attribute__((ext_vector_type(8))) short bf16x8;
typedef __attribute__((ext_vector_type(4))) float f32x4;

__device__ __forceinline__ float sigmoidf_(float x) { return 1.f / (1.f + __expf(-x)); }
__device__ __forceinline__ float softplusf_(float x) {
    return fmaxf(x, 0.f) + log1pf(__expf(-fabsf(x)));
}
// branchless round-to-nearest-even fp32 -> bf16 (inputs are finite)
__device__ __forceinline__ short f2bf(float f) {
    unsigned u = __float_as_uint(f);
    unsigned r = (u + 0x7FFFu + ((u >> 16) & 1u)) >> 16;
    return (short)r;
}

// ---------------------------------------------------------------------------
__global__ __launch_bounds__(256) void transpose_x_k(const float* __restrict__ x,
                                                     float* __restrict__ xt) {
    int i = blockIdx.x * 256 + threadIdx.x;
    if (i >= SEQ * BATCH * ENC_DIM) return;
    int e = i % ENC_DIM;
    int b = (i / ENC_DIM) % BATCH;
    int l = i / (ENC_DIM * BATCH);
    xt[((size_t)(b * SEQ + l)) * ENC_DIM + e] = x[i];
}

// ---------------------------------------------------------------------------
__global__ __launch_bounds__(256) void rmsnorm_k(const float* __restrict__ in,
                                                 const float* __restrict__ w,
                                                 float* __restrict__ out) {
    int row = blockIdx.x;
    const float* r = in + (size_t)row * D_MODEL;
    float s = 0.f;
    for (int i = threadIdx.x; i < D_MODEL; i += 256) { float v = r[i]; s += v * v; }
    for (int o = 32; o > 0; o >>= 1) s += __shfl_down(s, o);
    __shared__ float wsum[4];
    int wave = threadIdx.x >> 6;
    if ((threadIdx.x & 63) == 0) wsum[wave] = s;
    __syncthreads();
    float tot = wsum[0] + wsum[1] + wsum[2] + wsum[3];
    float scale = rsqrtf(tot / (float)D_MODEL + 1e-5f);
    for (int i = threadIdx.x; i < D_MODEL; i += 256)
        out[(size_t)row * D_MODEL + i] = r[i] * scale * w[i];
}

// ---------------------------------------------------------------------------
// bf16 MFMA NT GEMM: C[M,N] = A[M,K] @ B[N,K]^T, fp32 in/out, bf16 convert in
// staging, fp32 accumulate. BM=BN=128, BK=32, 256 threads (4 waves 2x2).
// LDS layout [kg][m][8] (kg = k/8): MFMA fragment = one ds_read_b128.
// MODE 0: store; 1: +bias[n]; 2: softplus(acc+bias[n]); 3: C += acc
// Requires M%128==0; N,K arbitrary (guarded); row strides multiple of 4 floats.
template<int MODE>
__global__ __launch_bounds__(256)
void gemm_bf16(const float* __restrict__ A, const float* __restrict__ B,
               const float* __restrict__ bias, float* __restrict__ C,
               int M, int N, int K, int lda, int ldb, int ldc)
{
    __shared__ short lA[4 * 128 * 8];   // 8 KB
    __shared__ short lB[4 * 128 * 8];   // 8 KB
    const int bm = blockIdx.x * 128;
    const int bn = blockIdx.y * 128;
    const int t = threadIdx.x;
    const int wave = t >> 6, lane = t & 63;
    const int wm = (wave >> 1) * 64, wn = (wave & 1) * 64;
    const int l15 = lane & 15, l4 = lane >> 4;

    const int row2 = t >> 1;          // 0..127: staged row within tile
    const int khalf = (t & 1) * 16;   // 0 or 16: staged k-halfchunk
    const int kgbase = khalf >> 3;    // 0 or 2

    f32x4 acc[4][4] = {};

    const int nkt = (K + 31) / 32;
    for (int kt = 0; kt < nkt; ++kt) {
        const int k0 = kt * 32 + khalf;
        // ---- stage A (128 x 32) ----
        {
            short v[16];
            const float* src = A + (size_t)(bm + row2) * lda + k0;
            if (k0 + 16 <= K) {
                #pragma unroll
                for (int j = 0; j < 16; j += 4) {
                    float4 f = *(const float4*)(src + j);
                    v[j + 0] = f2bf(f.x); v[j + 1] = f2bf(f.y);
                    v[j + 2] = f2bf(f.z); v[j + 3] = f2bf(f.w);
                }
            } else {
                #pragma unroll
                for (int j = 0; j < 16; ++j)
                    v[j] = (k0 + j < K) ? f2bf(src[j]) : (short)0;
            }
            short* dst = &lA[(kgbase * 128 + row2) * 8];
            *(bf16x8*)dst = *(const bf16x8*)&v[0];
            *(bf16x8*)(dst + 128 * 8) = *(const bf16x8*)&v[8];
        }
        // ---- stage B (128 x 32), N-guarded ----
        {
            short v[16];
            const int nrow = bn + row2;
            if (nrow < N) {
                const float* src = B + (size_t)nrow * ldb + k0;
                if (k0 + 16 <= K) {
                    #pragma unroll
                    for (int j = 0; j < 16; j += 4) {
                        float4 f = *(const float4*)(src + j);
                        v[j + 0] = f2bf(f.x); v[j + 1] = f2bf(f.y);
                        v[j + 2] = f2bf(f.z); v[j + 3] = f2bf(f.w);
                    }
                } else {
                    #pragma unroll
                    for (int j = 0; j < 16; ++j)
                        v[j] = (k0 + j < K) ? f2bf(src[j]) : (short)0;
                }
            } else {
                #pragma unroll
                for (int j = 0; j < 16; ++j) v[j] = 0;
            }
            short* dst = &lB[(kgbase * 128 + row2) * 8];
            *(bf16x8*)dst = *(const bf16x8*)&v[0];
            *(bf16x8*)(dst + 128 * 8) = *(const bf16x8*)&v[8];
        }
        __syncthreads();
        // ---- compute: 8 ds_read_b128 + 16 MFMA ----
        bf16x8 af[4], bfr[4];
        #pragma unroll
        for (int i = 0; i < 4; ++i)
            af[i] = *(const bf16x8*)&lA[(l4 * 128 + wm + i * 16 + l15) * 8];
        #pragma unroll
        for (int j = 0; j < 4; ++j)
            bfr[j] = *(const bf16x8*)&lB[(l4 * 128 + wn + j * 16 + l15) * 8];
        #pragma unroll
        for (int i = 0; i < 4; ++i)
            #pragma unroll
            for (int j = 0; j < 4; ++j)
                acc[i][j] = __builtin_amdgcn_mfma_f32_16x16x32_bf16(
                    af[i], bfr[j], acc[i][j], 0, 0, 0);
        __syncthreads();
    }

    // ---- epilogue: D row = l4*4 + reg, col = l15 within each 16x16 frag ----
    #pragma unroll
    for (int i = 0; i < 4; ++i) {
        #pragma unroll
        for (int r = 0; r < 4; ++r) {
            const int row = bm + wm + i * 16 + l4 * 4 + r;
            #pragma unroll
            for (int j = 0; j < 4; ++j) {
                const int col = bn + wn + j * 16 + l15;
                if (col < N) {
                    float v = acc[i][j][r];
                    if (MODE == 1) v += bias[col];
                    if (MODE == 2) v = softplusf_(v + bias[col]);
                    if (MODE == 3) v += C[(size_t)row * ldc + col];
                    C[(size_t)row * ldc + col] = v;
                }
            }
        }
    }
}

// ---------------------------------------------------------------------------
__global__ __launch_bounds__(256) void conv_silu_k(const float* __restrict__ xz,
                                                   const float* __restrict__ cw,
                                                   const float* __restrict__ cb,
                                                   float* __restrict__ xc) {
    int idx = blockIdx.x * 256 + threadIdx.x;
    if (idx >= NTOK * D_INNER) return;
    int d = idx % D_INNER;
    int m = idx / D_INNER;
    int l = m % SEQ;
    int b = m / SEQ;
    float acc = cb[d];
    #pragma unroll
    for (int j = 0; j < D_CONV; ++j) {
        int ll = l - (D_CONV - 1) + j;
        if (ll >= 0)
            acc = fmaf(cw[d * D_CONV + j], xz[(size_t)(b * SEQ + ll) * XZ_DIM + d], acc);
    }
    xc[(size_t)m * D_INNER + d] = acc * sigmoidf_(acc);
}

// ---------------------------------------------------------------------------
__global__ __launch_bounds__(256) void scan_k(const float* __restrict__ proj,
                                              const float* __restrict__ dtbuf,
                                              const float* __restrict__ xc,
                                              const float* __restrict__ xz,
                                              const float* __restrict__ A_log,
                                              const float* __restrict__ Dvec,
                                              float* __restrict__ y) {
    int t = blockIdx.x * 256 + threadIdx.x;
    int s = t & (D_STATE - 1);
    int ch = t >> 4;
    int d = ch % D_INNER;
    int b = ch / D_INNER;
    float A = -__expf(A_log[d * D_STATE + s]);
    float Dv = Dvec[d];
    float state = 0.f;
    #pragma unroll 2
    for (int l = 0; l < SEQ; ++l) {
        int m = b * SEQ + l;
        float dtv = dtbuf[(size_t)m * D_INNER + d];
        float xcv = xc[(size_t)m * D_INNER + d];
        float Bv = proj[(size_t)m * PROJ_DIM + DT_RANK + s];
        float Cv = proj[(size_t)m * PROJ_DIM + DT_RANK + D_STATE + s];
        float da = __expf(dtv * A);
        state = fmaf(da, state, dtv * Bv * xcv);
        float contrib = state * Cv;
        contrib += __shfl_xor(contrib, 1);
        contrib += __shfl_xor(contrib, 2);
        contrib += __shfl_xor(contrib, 4);
        contrib += __shfl_xor(contrib, 8);
        if (s == 0) {
            float zv = xz[(size_t)m * XZ_DIM + D_INNER + d];
            float yv = (contrib + Dv * xcv) * (zv * sigmoidf_(zv));
            y[(size_t)m * D_INNER + d] = yv;
        }
    }
}

// ---------------------------------------------------------------------------
extern "C" void kernel_launch(void* const* d_in, const int* in_sizes, int n_in,
                              void* d_out, int out_size, void* d_ws, size_t ws_size,
                              hipStream_t stream) {
    const float* x           = (const float*)d_in[0];
    const float* W_et        = (const float*)d_in[1];
    const float* b_et        = (const float*)d_in[2];
    const float* in_proj_w   = (const float*)d_in[3];
    const float* conv_w      = (const float*)d_in[4];
    const float* conv_b      = (const float*)d_in[5];
    const float* x_proj_w    = (const float*)d_in[6];
    const float* dt_proj_w   = (const float*)d_in[7];
    const float* dt_proj_b   = (const float*)d_in[8];
    const float* A_log       = (const float*)d_in[9];
    const float* Dv          = (const float*)d_in[10];
    const float* out_proj_w  = (const float*)d_in[11];
    const float* norm_w      = (const float*)d_in[12];
    const float* final_norm_w= (const float*)d_in[13];
    const float* embed       = (const float*)d_in[14];
    float* out = (float*)d_out;
    float* ws  = (float*)d_ws;

    float* h    = ws;
    float* hn   = h    + (size_t)NTOK * D_MODEL;
    float* xz   = hn   + (size_t)NTOK * D_MODEL;
    float* xc   = xz   + (size_t)NTOK * XZ_DIM;
    float* proj = xc   + (size_t)NTOK * D_INNER;
    float* dt   = proj + (size_t)NTOK * PROJ_DIM;
    float* yb   = dt   + (size_t)NTOK * D_INNER;

    dim3 blk(256);

    transpose_x_k<<<(SEQ * BATCH * ENC_DIM + 255) / 256, blk, 0, stream>>>(x, yb);
    gemm_bf16<1><<<dim3(NTOK / 128, (D_MODEL + 127) / 128), blk, 0, stream>>>(
        yb, W_et, b_et, h, NTOK, D_MODEL, ENC_DIM, ENC_DIM, ENC_DIM, D_MODEL);

    for (int L = 0; L < N_LAYERS; ++L) {
        const float* in_w = in_proj_w  + (size_t)L * XZ_DIM * D_MODEL;
        const float* cw   = conv_w     + (size_t)L * D_INNER * D_CONV;
        const float* cb   = conv_b     + (size_t)L * D_INNER;
        const float* xw   = x_proj_w   + (size_t)L * PROJ_DIM * D_INNER;
        const float* dtw  = dt_proj_w  + (size_t)L * D_INNER * DT_RANK;
        const float* dtb  = dt_proj_b  + (size_t)L * D_INNER;
        const float* Al   = A_log      + (size_t)L * D_INNER * D_STATE;
        const float* Dl   = Dv         + (size_t)L * D_INNER;
        const float* ow   = out_proj_w + (size_t)L * D_MODEL * D_INNER;
        const float* nw   = norm_w     + (size_t)L * D_MODEL;

        rmsnorm_k<<<NTOK, blk, 0, stream>>>(h, nw, hn);
        gemm_bf16<0><<<dim3(NTOK / 128, XZ_DIM / 128), blk, 0, stream>>>(
            hn, in_w, nullptr, xz, NTOK, XZ_DIM, D_MODEL, D_MODEL, D_MODEL, XZ_DIM);
        conv_silu_k<<<(NTOK * D_INNER + 255) / 256, blk, 0, stream>>>(xz, cw, cb, xc);
        gemm_bf16<0><<<dim3(NTOK / 128, (PROJ_DIM + 127) / 128), blk, 0, stream>>>(
            xc, xw, nullptr, proj, NTOK, PROJ_DIM, D_INNER, D_INNER, D_INNER, PROJ_DIM);
        gemm_bf16<2><<<dim3(NTOK / 128, D_INNER / 128), blk, 0, stream>>>(
            proj, dtw, dtb, dt, NTOK, D_INNER, DT_RANK, PROJ_DIM, DT_RANK, D_INNER);
        scan_k<<<(BATCH * D_INNER * D_STATE) / 256, blk, 0, stream>>>(
            proj, dt, xc, xz, Al, Dl, yb);
        gemm_bf16<3><<<dim3(NTOK / 128, D_MODEL / 128), blk, 0, stream>>>(
            yb, ow, nullptr, h, NTOK, D_MODEL, D_INNER, D_INNER, D_INNER, D_MODEL);
    }

    rmsnorm_k<<<NTOK, blk, 0, stream>>>(h, final_norm_w, hn);
    gemm_bf16<0><<<dim3(NTOK / 128, (VOCAB + 127) / 128), blk, 0, stream>>>(
        hn, embed, nullptr, out, NTOK, VOCAB, D_MODEL, D_MODEL, D_MODEL, VOCAB);
}

// Round 3
// 7987.438 us; speedup vs baseline: 2.2534x; 2.0181x over previous
//
#include <hip/hip_runtime.h>
#include <math.h>

#define N_LAYERS 24
#define D_MODEL 768
#define D_INNER 1536
#define D_STATE 16
#define DT_RANK 48
#define D_CONV 4
#define VOCAB 50280
#define ENC_DIM 256
#define SEQ 512
#define BATCH 2
#define NTOK (SEQ*BATCH)
#define XZ_DIM (2*D_INNER)
#define PROJ_DIM (DT_RANK + 2*D_STATE)  // 80
#define DTW_PAD 64                       // dt_proj K padded 48 -> 64

typedef __attribute__((ext_vector_type(8))) short bf16x8;
typedef __attribute__((ext_vector_type(4))) float f32x4;

__device__ __forceinline__ float sigmoidf_(float x) { return 1.f / (1.f + __expf(-x)); }
__device__ __forceinline__ float softplusf_(float x) {
    return fmaxf(x, 0.f) + log1pf(__expf(-fabsf(x)));
}
__device__ __forceinline__ short f2bf(float f) {
    unsigned u = __float_as_uint(f);
    unsigned r = (u + 0x7FFFu + ((u >> 16) & 1u)) >> 16;
    return (short)r;
}
__device__ __forceinline__ void load_lds16(const void* g, void* l) {
    __builtin_amdgcn_global_load_lds((const __attribute__((address_space(1))) void*)g,
                                     (__attribute__((address_space(3))) void*)l, 16, 0, 0);
}

// ---------------------------------------------------------------------------
// fp32 -> bf16 bulk convert (n % 4 == 0 for all uses, guarded anyway)
__global__ __launch_bounds__(256) void cvt_k(const float* __restrict__ s,
                                             short* __restrict__ d, int n) {
    int stride = gridDim.x * 256 * 4;
    for (int i = (blockIdx.x * 256 + threadIdx.x) * 4; i + 3 < n; i += stride) {
        float4 f = *(const float4*)(s + i);
        short4 o; o.x = f2bf(f.x); o.y = f2bf(f.y); o.z = f2bf(f.z); o.w = f2bf(f.w);
        *(short4*)(d + i) = o;
    }
}

// dt_proj weights: [L][1536][48] fp32 -> [L][1536][64] bf16 zero-padded
__global__ __launch_bounds__(256) void pad_dtw_k(const float* __restrict__ src,
                                                 short* __restrict__ dst) {
    int i = blockIdx.x * 256 + threadIdx.x;
    if (i >= N_LAYERS * D_INNER * DTW_PAD) return;
    int k = i & (DTW_PAD - 1);
    int rest = i >> 6;            // L*D_INNER + d
    dst[i] = (k < DT_RANK) ? f2bf(src[(size_t)rest * DT_RANK + k]) : (short)0;
}

// ---------------------------------------------------------------------------
__global__ __launch_bounds__(256) void transpose_x_k(const float* __restrict__ x,
                                                     float* __restrict__ xt) {
    int i = blockIdx.x * 256 + threadIdx.x;
    if (i >= SEQ * BATCH * ENC_DIM) return;
    int e = i % ENC_DIM;
    int b = (i / ENC_DIM) % BATCH;
    int l = i / (ENC_DIM * BATCH);
    xt[((size_t)(b * SEQ + l)) * ENC_DIM + e] = x[i];
}
__global__ __launch_bounds__(256) void transpose_x_bf_k(const float* __restrict__ x,
                                                        short* __restrict__ xt) {
    int i = blockIdx.x * 256 + threadIdx.x;
    if (i >= SEQ * BATCH * ENC_DIM) return;
    int e = i % ENC_DIM;
    int b = (i / ENC_DIM) % BATCH;
    int l = i / (ENC_DIM * BATCH);
    xt[((size_t)(b * SEQ + l)) * ENC_DIM + e] = f2bf(x[i]);
}

// ---------------------------------------------------------------------------
// RMSNorm: fp32-out (tier B) and bf16-out (tier A) variants
__device__ __forceinline__ float rms_scale(const float* r, int tid) {
    float s = 0.f;
    for (int i = tid; i < D_MODEL; i += 256) { float v = r[i]; s += v * v; }
    for (int o = 32; o > 0; o >>= 1) s += __shfl_down(s, o);
    __shared__ float wsum[4];
    if ((tid & 63) == 0) wsum[tid >> 6] = s;
    __syncthreads();
    float tot = wsum[0] + wsum[1] + wsum[2] + wsum[3];
    return rsqrtf(tot / (float)D_MODEL + 1e-5f);
}
__global__ __launch_bounds__(256) void rmsnorm_k(const float* __restrict__ in,
                                                 const float* __restrict__ w,
                                                 float* __restrict__ out) {
    int row = blockIdx.x;
    const float* r = in + (size_t)row * D_MODEL;
    float sc = rms_scale(r, threadIdx.x);
    for (int i = threadIdx.x; i < D_MODEL; i += 256)
        out[(size_t)row * D_MODEL + i] = r[i] * sc * w[i];
}
__global__ __launch_bounds__(256) void rmsnorm_bf_k(const float* __restrict__ in,
                                                    const float* __restrict__ w,
                                                    short* __restrict__ out) {
    int row = blockIdx.x;
    const float* r = in + (size_t)row * D_MODEL;
    float sc = rms_scale(r, threadIdx.x);
    for (int i = threadIdx.x; i < D_MODEL; i += 256)
        out[(size_t)row * D_MODEL + i] = f2bf(r[i] * sc * w[i]);
}

// ---------------------------------------------------------------------------
// bf16 x bf16 -> fp32 MFMA NT GEMM with global_load_lds staging.
// A[M][ldaE] bf16, B[N][ldbE] bf16, C[M][ldc] fp32.
// BM=BN=128, BK=32, 256 threads (2x2 waves of 64x64).
// LDS layout [kg(0..3)][row(0..127)][8 bf16]; staged by wave w covering kg=w.
// Requires M%128==0, K%32==0; N guarded (OOB B rows clamp to row 0, cols
// discarded in epilogue).
// MODE 0: store; 1: +bias; 2: softplus(acc+bias); 3: C += acc;
// MODE 4: store fp32 + bf16 dual-store to Cb[ldcb].
template<int MODE>
__global__ __launch_bounds__(256)
void gemm_bb(const short* __restrict__ A, const short* __restrict__ B,
             const float* __restrict__ bias, float* __restrict__ C,
             short* __restrict__ Cb,
             int M, int N, int K, int ldaE, int ldbE, int ldc, int ldcb)
{
    __shared__ short lA[4 * 128 * 8];   // 8 KB
    __shared__ short lB[4 * 128 * 8];   // 8 KB
    const int bm = blockIdx.x * 128;
    const int bn = blockIdx.y * 128;
    const int t = threadIdx.x;
    const int wave = t >> 6, lane = t & 63;
    const int wm = (wave >> 1) * 64, wn = (wave & 1) * 64;
    const int l15 = lane & 15, l4 = lane >> 4;

    f32x4 acc[4][4] = {};
    const int nkt = K / 32;

    for (int kt = 0; kt < nkt; ++kt) {
        const int k0 = kt * 32;
        // stage A: wave w covers kg=w; two 64-row halves
        #pragma unroll
        for (int rr = 0; rr < 2; ++rr) {
            const int rowblk = rr * 64;
            const int arow = bm + rowblk + lane;
            load_lds16(A + (size_t)arow * ldaE + k0 + wave * 8,
                       &lA[(wave * 128 + rowblk) * 8]);
            int brow = bn + rowblk + lane;
            if (brow >= N) brow = 0;     // harmless clamp; cols guarded at store
            load_lds16(B + (size_t)brow * ldbE + k0 + wave * 8,
                       &lB[(wave * 128 + rowblk) * 8]);
        }
        __syncthreads();
        bf16x8 af[4], bfr[4];
        #pragma unroll
        for (int i = 0; i < 4; ++i)
            af[i] = *(const bf16x8*)&lA[(l4 * 128 + wm + i * 16 + l15) * 8];
        #pragma unroll
        for (int j = 0; j < 4; ++j)
            bfr[j] = *(const bf16x8*)&lB[(l4 * 128 + wn + j * 16 + l15) * 8];
        #pragma unroll
        for (int i = 0; i < 4; ++i)
            #pragma unroll
            for (int j = 0; j < 4; ++j)
                acc[i][j] = __builtin_amdgcn_mfma_f32_16x16x32_bf16(
                    af[i], bfr[j], acc[i][j], 0, 0, 0);
        __syncthreads();
    }

    #pragma unroll
    for (int i = 0; i < 4; ++i) {
        #pragma unroll
        for (int r = 0; r < 4; ++r) {
            const int row = bm + wm + i * 16 + l4 * 4 + r;
            #pragma unroll
            for (int j = 0; j < 4; ++j) {
                const int col = bn + wn + j * 16 + l15;
                if (col < N) {
                    float v = acc[i][j][r];
                    if (MODE == 1) v += bias[col];
                    if (MODE == 2) v = softplusf_(v + bias[col]);
                    if (MODE == 3) v += C[(size_t)row * ldc + col];
                    C[(size_t)row * ldc + col] = v;
                    if (MODE == 4) Cb[(size_t)row * ldcb + col] = f2bf(v);
                }
            }
        }
    }
}

// ---------------------------------------------------------------------------
// Round-2 fallback GEMM (fp32 in, converts in staging) — tier B only.
template<int MODE>
__global__ __launch_bounds__(256)
void gemm_bf16(const float* __restrict__ A, const float* __restrict__ B,
               const float* __restrict__ bias, float* __restrict__ C,
               int M, int N, int K, int lda, int ldb, int ldc)
{
    __shared__ short lA[4 * 128 * 8];
    __shared__ short lB[4 * 128 * 8];
    const int bm = blockIdx.x * 128;
    const int bn = blockIdx.y * 128;
    const int t = threadIdx.x;
    const int wave = t >> 6, lane = t & 63;
    const int wm = (wave >> 1) * 64, wn = (wave & 1) * 64;
    const int l15 = lane & 15, l4 = lane >> 4;
    const int row2 = t >> 1;
    const int khalf = (t & 1) * 16;
    const int kgbase = khalf >> 3;
    f32x4 acc[4][4] = {};
    const int nkt = (K + 31) / 32;
    for (int kt = 0; kt < nkt; ++kt) {
        const int k0 = kt * 32 + khalf;
        {
            short v[16];
            const float* src = A + (size_t)(bm + row2) * lda + k0;
            if (k0 + 16 <= K) {
                #pragma unroll
                for (int j = 0; j < 16; j += 4) {
                    float4 f = *(const float4*)(src + j);
                    v[j+0]=f2bf(f.x); v[j+1]=f2bf(f.y); v[j+2]=f2bf(f.z); v[j+3]=f2bf(f.w);
                }
            } else {
                #pragma unroll
                for (int j = 0; j < 16; ++j)
                    v[j] = (k0 + j < K) ? f2bf(src[j]) : (short)0;
            }
            short* dst = &lA[(kgbase * 128 + row2) * 8];
            *(bf16x8*)dst = *(const bf16x8*)&v[0];
            *(bf16x8*)(dst + 128 * 8) = *(const bf16x8*)&v[8];
        }
        {
            short v[16];
            const int nrow = bn + row2;
            if (nrow < N) {
                const float* src = B + (size_t)nrow * ldb + k0;
                if (k0 + 16 <= K) {
                    #pragma unroll
                    for (int j = 0; j < 16; j += 4) {
                        float4 f = *(const float4*)(src + j);
                        v[j+0]=f2bf(f.x); v[j+1]=f2bf(f.y); v[j+2]=f2bf(f.z); v[j+3]=f2bf(f.w);
                    }
                } else {
                    #pragma unroll
                    for (int j = 0; j < 16; ++j)
                        v[j] = (k0 + j < K) ? f2bf(src[j]) : (short)0;
                }
            } else {
                #pragma unroll
                for (int j = 0; j < 16; ++j) v[j] = 0;
            }
            short* dst = &lB[(kgbase * 128 + row2) * 8];
            *(bf16x8*)dst = *(const bf16x8*)&v[0];
            *(bf16x8*)(dst + 128 * 8) = *(const bf16x8*)&v[8];
        }
        __syncthreads();
        bf16x8 af[4], bfr[4];
        #pragma unroll
        for (int i = 0; i < 4; ++i)
            af[i] = *(const bf16x8*)&lA[(l4 * 128 + wm + i * 16 + l15) * 8];
        #pragma unroll
        for (int j = 0; j < 4; ++j)
            bfr[j] = *(const bf16x8*)&lB[(l4 * 128 + wn + j * 16 + l15) * 8];
        #pragma unroll
        for (int i = 0; i < 4; ++i)
            #pragma unroll
            for (int j = 0; j < 4; ++j)
                acc[i][j] = __builtin_amdgcn_mfma_f32_16x16x32_bf16(
                    af[i], bfr[j], acc[i][j], 0, 0, 0);
        __syncthreads();
    }
    #pragma unroll
    for (int i = 0; i < 4; ++i) {
        #pragma unroll
        for (int r = 0; r < 4; ++r) {
            const int row = bm + wm + i * 16 + l4 * 4 + r;
            #pragma unroll
            for (int j = 0; j < 4; ++j) {
                const int col = bn + wn + j * 16 + l15;
                if (col < N) {
                    float v = acc[i][j][r];
                    if (MODE == 1) v += bias[col];
                    if (MODE == 2) v = softplusf_(v + bias[col]);
                    if (MODE == 3) v += C[(size_t)row * ldc + col];
                    C[(size_t)row * ldc + col] = v;
                }
            }
        }
    }
}

// ---------------------------------------------------------------------------
// Depthwise causal conv (k=4) + bias + SiLU. DUAL: dual bf16 store for GEMM-A.
template<int DUAL>
__global__ __launch_bounds__(256) void conv_silu_k(const float* __restrict__ xz,
                                                   const float* __restrict__ cw,
                                                   const float* __restrict__ cb,
                                                   float* __restrict__ xc,
                                                   short* __restrict__ xcb) {
    int idx = blockIdx.x * 256 + threadIdx.x;
    if (idx >= NTOK * D_INNER) return;
    int d = idx % D_INNER;
    int m = idx / D_INNER;
    int l = m % SEQ;
    int b = m / SEQ;
    float acc = cb[d];
    #pragma unroll
    for (int j = 0; j < D_CONV; ++j) {
        int ll = l - (D_CONV - 1) + j;
        if (ll >= 0)
            acc = fmaf(cw[d * D_CONV + j], xz[(size_t)(b * SEQ + ll) * XZ_DIM + d], acc);
    }
    float v = acc * sigmoidf_(acc);
    xc[(size_t)m * D_INNER + d] = v;
    if (DUAL) xcb[(size_t)m * D_INNER + d] = f2bf(v);
}

// ---------------------------------------------------------------------------
// Fused chunked selective scan. One block per (b,d) channel: 256 threads =
// 16 chunks x 16 states. Phase 1: chunk-local (P = prod decay, S = local
// state) in registers -> LDS. Carry for chunk c = fold of chunks < c.
// Phase 2: re-scan with carry, emit y = (sum_s state*C + D*xc) * silu(z).
template<int BFOUT>
__global__ __launch_bounds__(256) void scan2_k(const float* __restrict__ proj,
                                               const float* __restrict__ dtb,
                                               const float* __restrict__ xc,
                                               const float* __restrict__ xz,
                                               const float* __restrict__ A_log,
                                               const float* __restrict__ Dvec,
                                               void* __restrict__ yout) {
    __shared__ float lp[256], ls[256];
    const int ch = blockIdx.x;
    const int d = ch % D_INNER;
    const int b = ch / D_INNER;
    const int t = threadIdx.x;
    const int s = t & 15;
    const int c = t >> 4;
    const float A = -__expf(A_log[d * D_STATE + s]);
    const int m0 = b * SEQ + c * 32;
    float P = 1.f, S = 0.f;
    for (int i = 0; i < 32; ++i) {
        int m = m0 + i;
        float dtv = dtb[(size_t)m * D_INNER + d];
        float xcv = xc[(size_t)m * D_INNER + d];
        float Bv  = proj[(size_t)m * PROJ_DIM + DT_RANK + s];
        float da = __expf(dtv * A);
        S = fmaf(da, S, dtv * Bv * xcv);
        P *= da;
    }
    lp[c * 16 + s] = P;
    ls[c * 16 + s] = S;
    __syncthreads();
    float carry = 0.f;
    for (int j = 0; j < c; ++j)
        carry = fmaf(lp[j * 16 + s], carry, ls[j * 16 + s]);
    const float Dv = Dvec[d];
    float state = carry;
    for (int i = 0; i < 32; ++i) {
        int m = m0 + i;
        float dtv = dtb[(size_t)m * D_INNER + d];
        float xcv = xc[(size_t)m * D_INNER + d];
        float Bv  = proj[(size_t)m * PROJ_DIM + DT_RANK + s];
        float Cv  = proj[(size_t)m * PROJ_DIM + DT_RANK + D_STATE + s];
        float da = __expf(dtv * A);
        state = fmaf(da, state, dtv * Bv * xcv);
        float contrib = state * Cv;
        contrib += __shfl_xor(contrib, 1);
        contrib += __shfl_xor(contrib, 2);
        contrib += __shfl_xor(contrib, 4);
        contrib += __shfl_xor(contrib, 8);
        if (s == 0) {
            float zv = xz[(size_t)m * XZ_DIM + D_INNER + d];
            float yv = (contrib + Dv * xcv) * (zv * sigmoidf_(zv));
            if (BFOUT) ((short*)yout)[(size_t)m * D_INNER + d] = f2bf(yv);
            else       ((float*)yout)[(size_t)m * D_INNER + d] = yv;
        }
    }
}

// ---------------------------------------------------------------------------
extern "C" void kernel_launch(void* const* d_in, const int* in_sizes, int n_in,
                              void* d_out, int out_size, void* d_ws, size_t ws_size,
                              hipStream_t stream) {
    const float* x           = (const float*)d_in[0];
    const float* W_et        = (const float*)d_in[1];
    const float* b_et        = (const float*)d_in[2];
    const float* in_proj_w   = (const float*)d_in[3];
    const float* conv_w      = (const float*)d_in[4];
    const float* conv_b      = (const float*)d_in[5];
    const float* x_proj_w    = (const float*)d_in[6];
    const float* dt_proj_w   = (const float*)d_in[7];
    const float* dt_proj_b   = (const float*)d_in[8];
    const float* A_log       = (const float*)d_in[9];
    const float* Dv          = (const float*)d_in[10];
    const float* out_proj_w  = (const float*)d_in[11];
    const float* norm_w      = (const float*)d_in[12];
    const float* final_norm_w= (const float*)d_in[13];
    const float* embed       = (const float*)d_in[14];
    float* out = (float*)d_out;
    float* ws  = (float*)d_ws;

    // fp32 block (round-2-compatible layout)
    float* h    = ws;
    float* hn   = h    + (size_t)NTOK * D_MODEL;
    float* xz   = hn   + (size_t)NTOK * D_MODEL;
    float* xc   = xz   + (size_t)NTOK * XZ_DIM;
    float* proj = xc   + (size_t)NTOK * D_INNER;
    float* dt   = proj + (size_t)NTOK * PROJ_DIM;
    float* yb   = dt   + (size_t)NTOK * D_INNER;
    // tier-A bf16 block
    short* xt_bf   = (short*)(yb + (size_t)NTOK * D_INNER);
    short* hn_bf   = xt_bf   + (size_t)NTOK * ENC_DIM;
    short* xc_bf   = hn_bf   + (size_t)NTOK * D_MODEL;
    short* proj_bf = xc_bf   + (size_t)NTOK * D_INNER;
    short* yb_bf   = proj_bf + (size_t)NTOK * PROJ_DIM;
    short* wet_bf  = yb_bf   + (size_t)NTOK * D_INNER;
    short* inw_bf  = wet_bf  + (size_t)D_MODEL * ENC_DIM;
    short* xw_bf   = inw_bf  + (size_t)N_LAYERS * XZ_DIM * D_MODEL;
    short* dtw_bf  = xw_bf   + (size_t)N_LAYERS * PROJ_DIM * D_INNER;
    short* ow_bf   = dtw_bf  + (size_t)N_LAYERS * D_INNER * DTW_PAD;
    short* emb_bf  = ow_bf   + (size_t)N_LAYERS * D_MODEL * D_INNER;
    short* end_bf  = emb_bf  + (size_t)VOCAB * D_MODEL;
    size_t needA = (size_t)((char*)end_bf - (char*)d_ws);
    bool tierA = ws_size >= needA;

    dim3 blk(256);

    if (tierA) {
        // ---- preconvert weights to bf16 ----
        auto cvt = [&](const float* s, short* d, size_t n) {
            int nb = (int)((n / 4 + 255) / 256); if (nb > 2048) nb = 2048;
            cvt_k<<<nb, blk, 0, stream>>>(s, d, (int)n);
        };
        cvt(W_et, wet_bf, (size_t)D_MODEL * ENC_DIM);
        cvt(in_proj_w, inw_bf, (size_t)N_LAYERS * XZ_DIM * D_MODEL);
        cvt(x_proj_w, xw_bf, (size_t)N_LAYERS * PROJ_DIM * D_INNER);
        cvt(out_proj_w, ow_bf, (size_t)N_LAYERS * D_MODEL * D_INNER);
        cvt(embed, emb_bf, (size_t)VOCAB * D_MODEL);
        pad_dtw_k<<<(N_LAYERS * D_INNER * DTW_PAD + 255) / 256, blk, 0, stream>>>(
            dt_proj_w, dtw_bf);

        // ---- encoder ----
        transpose_x_bf_k<<<(SEQ * BATCH * ENC_DIM + 255) / 256, blk, 0, stream>>>(x, xt_bf);
        gemm_bb<1><<<dim3(NTOK / 128, D_MODEL / 128), blk, 0, stream>>>(
            xt_bf, wet_bf, b_et, h, nullptr,
            NTOK, D_MODEL, ENC_DIM, ENC_DIM, ENC_DIM, D_MODEL, 0);

        for (int L = 0; L < N_LAYERS; ++L) {
            const short* in_w = inw_bf + (size_t)L * XZ_DIM * D_MODEL;
            const float* cw   = conv_w + (size_t)L * D_INNER * D_CONV;
            const float* cb   = conv_b + (size_t)L * D_INNER;
            const short* xw   = xw_bf  + (size_t)L * PROJ_DIM * D_INNER;
            const short* dtw  = dtw_bf + (size_t)L * D_INNER * DTW_PAD;
            const float* dtbp = dt_proj_b + (size_t)L * D_INNER;
            const float* Al   = A_log  + (size_t)L * D_INNER * D_STATE;
            const float* Dl   = Dv     + (size_t)L * D_INNER;
            const short* ow   = ow_bf  + (size_t)L * D_MODEL * D_INNER;
            const float* nw   = norm_w + (size_t)L * D_MODEL;

            rmsnorm_bf_k<<<NTOK, blk, 0, stream>>>(h, nw, hn_bf);
            gemm_bb<0><<<dim3(NTOK / 128, XZ_DIM / 128), blk, 0, stream>>>(
                hn_bf, in_w, nullptr, xz, nullptr,
                NTOK, XZ_DIM, D_MODEL, D_MODEL, D_MODEL, XZ_DIM, 0);
            conv_silu_k<1><<<(NTOK * D_INNER + 255) / 256, blk, 0, stream>>>(
                xz, cw, cb, xc, xc_bf);
            gemm_bb<4><<<dim3(NTOK / 128, 1), blk, 0, stream>>>(
                xc_bf, xw, nullptr, proj, proj_bf,
                NTOK, PROJ_DIM, D_INNER, D_INNER, D_INNER, PROJ_DIM, PROJ_DIM);
            gemm_bb<2><<<dim3(NTOK / 128, D_INNER / 128), blk, 0, stream>>>(
                proj_bf, dtw, dtbp, dt, nullptr,
                NTOK, D_INNER, DTW_PAD, PROJ_DIM, DTW_PAD, D_INNER, 0);
            scan2_k<1><<<BATCH * D_INNER, blk, 0, stream>>>(
                proj, dt, xc, xz, Al, Dl, yb_bf);
            gemm_bb<3><<<dim3(NTOK / 128, D_MODEL / 128), blk, 0, stream>>>(
                yb_bf, ow, nullptr, h, nullptr,
                NTOK, D_MODEL, D_INNER, D_INNER, D_INNER, D_MODEL, 0);
        }

        rmsnorm_bf_k<<<NTOK, blk, 0, stream>>>(h, final_norm_w, hn_bf);
        gemm_bb<0><<<dim3(NTOK / 128, (VOCAB + 127) / 128), blk, 0, stream>>>(
            hn_bf, emb_bf, nullptr, out, nullptr,
            NTOK, VOCAB, D_MODEL, D_MODEL, D_MODEL, VOCAB, 0);
    } else {
        // ---- tier B fallback: round-2 path + fused chunked scan ----
        transpose_x_k<<<(SEQ * BATCH * ENC_DIM + 255) / 256, blk, 0, stream>>>(x, yb);
        gemm_bf16<1><<<dim3(NTOK / 128, D_MODEL / 128), blk, 0, stream>>>(
            yb, W_et, b_et, h, NTOK, D_MODEL, ENC_DIM, ENC_DIM, ENC_DIM, D_MODEL);
        for (int L = 0; L < N_LAYERS; ++L) {
            const float* in_w = in_proj_w  + (size_t)L * XZ_DIM * D_MODEL;
            const float* cw   = conv_w     + (size_t)L * D_INNER * D_CONV;
            const float* cb   = conv_b     + (size_t)L * D_INNER;
            const float* xw   = x_proj_w   + (size_t)L * PROJ_DIM * D_INNER;
            const float* dtw  = dt_proj_w  + (size_t)L * D_INNER * DT_RANK;
            const float* dtbp = dt_proj_b  + (size_t)L * D_INNER;
            const float* Al   = A_log      + (size_t)L * D_INNER * D_STATE;
            const float* Dl   = Dv         + (size_t)L * D_INNER;
            const float* ow   = out_proj_w + (size_t)L * D_MODEL * D_INNER;
            const float* nw   = norm_w     + (size_t)L * D_MODEL;
            rmsnorm_k<<<NTOK, blk, 0, stream>>>(h, nw, hn);
            gemm_bf16<0><<<dim3(NTOK / 128, XZ_DIM / 128), blk, 0, stream>>>(
                hn, in_w, nullptr, xz, NTOK, XZ_DIM, D_MODEL, D_MODEL, D_MODEL, XZ_DIM);
            conv_silu_k<0><<<(NTOK * D_INNER + 255) / 256, blk, 0, stream>>>(
                xz, cw, cb, xc, nullptr);
            gemm_bf16<0><<<dim3(NTOK / 128, 1), blk, 0, stream>>>(
                xc, xw, nullptr, proj, NTOK, PROJ_DIM, D_INNER, D_INNER, D_INNER, PROJ_DIM);
            gemm_bf16<2><<<dim3(NTOK / 128, D_INNER / 128), blk, 0, stream>>>(
                proj, dtw, dtbp, dt, NTOK, D_INNER, DT_RANK, PROJ_DIM, DT_RANK, D_INNER);
            scan2_k<0><<<BATCH * D_INNER, blk, 0, stream>>>(
                proj, dt, xc, xz, Al, Dl, yb);
            gemm_bf16<3><<<dim3(NTOK / 128, D_MODEL / 128), blk, 0, stream>>>(
                yb, ow, nullptr, h, NTOK, D_MODEL, D_INNER, D_INNER, D_INNER, D_MODEL);
        }
        rmsnorm_k<<<NTOK, blk, 0, stream>>>(h, final_norm_w, hn);
        gemm_bf16<0><<<dim3(NTOK / 128, (VOCAB + 127) / 128), blk, 0, stream>>>(
            hn, embed, nullptr, out, NTOK, VOCAB, D_MODEL, D_MODEL, D_MODEL, VOCAB);
    }
}